// Round 6
// baseline (2017.147 us; speedup 1.0000x reference)
//
#include <hip/hip_runtime.h>
#include <hip/hip_bf16.h>

// Problem constants (fixed by reference)
#define BN 16
#define CC 64
#define HH 128
#define WW 128
#define HW 16384
#define C3 192
#define NHEADS 8

// NOTE: launcher processes batches in 2 groups of 8 (workspace ~172 MB).

// ---------------------------------------------------------------------------
// K12: FUSED qkv 1x1 conv + depthwise 3x3 (pad 1).
// Block = 16x16 output tile x 32 qkv channels x one b.
// Phase A: 1x1 conv on 18x18 haloed tile -> sm_q (LDS), y staged 8ch at a time.
// Phase B: depthwise 3x3 entirely from LDS, write final qkv.
// Eliminates the bufT round trip (400 MB/group) and 3x re-read of y.
// ---------------------------------------------------------------------------
__global__ __launch_bounds__(256) void k_qkvdw(const float* __restrict__ y,
                                               const float* __restrict__ w_qkv,
                                               const float* __restrict__ w_dw,
                                               float* __restrict__ qkvB) {
    __shared__ __align__(16) float sm_w1[64 * 32];   // [c][o]   8 KB
    __shared__ __align__(16) float sm_y[8 * 324];    // 8ch x 18x18, 10.1 KB
    __shared__ __align__(16) float sm_q[32 * 324];   // 32ch x 18x18, 41.5 KB
    __shared__ float sm_wd[32 * 9];                  // 1.1 KB
    int tid = threadIdx.x;
    int bid = blockIdx.x;           // 8b * 64tile * 6chunk = 3072
    int b = bid / 384;
    int rem = bid - b * 384;
    int tile = rem / 6;             // chunk innermost: 6 consecutive blocks
    int q32 = rem - tile * 6;       // share the same y tile (L1/L2 reuse)
    int ty0 = (tile >> 3) * 16, tx0 = (tile & 7) * 16;

    for (int i = tid; i < 2048; i += 256) {
        int c = i >> 5, o = i & 31;
        sm_w1[i] = w_qkv[(size_t)(q32 * 32 + o) * 64 + c];
    }
    for (int i = tid; i < 288; i += 256)
        sm_wd[i] = w_dw[(size_t)(q32 * 32) * 9 + i];

    const float* yb = y + (size_t)b * CC * HW;
    float acc0[32], acc1[32];
#pragma unroll
    for (int o = 0; o < 32; ++o) { acc0[o] = 0.f; acc1[o] = 0.f; }
    bool p2 = tid < 68;             // second pixel pass covers px 256..323

    for (int c8 = 0; c8 < 8; ++c8) {
        __syncthreads();            // protect sm_y from previous iter readers
        for (int i = tid; i < 2592; i += 256) {
            int c = i / 324;
            int p = i - c * 324;
            int r = p / 18, q = p - r * 18;
            int yy = ty0 + r - 1, xx = tx0 + q - 1;
            sm_y[i] = ((unsigned)yy < 128u && (unsigned)xx < 128u)
                          ? yb[(size_t)(c8 * 8 + c) * HW + yy * 128 + xx] : 0.f;
        }
        __syncthreads();
#pragma unroll
        for (int cc = 0; cc < 8; ++cc) {
            float yv0 = sm_y[cc * 324 + tid];
            float yv1 = p2 ? sm_y[cc * 324 + 256 + tid] : 0.f;
            const float* wr = &sm_w1[(c8 * 8 + cc) * 32];
#pragma unroll
            for (int o4 = 0; o4 < 8; ++o4) {
                float4 w = *(const float4*)(wr + o4 * 4);
                acc0[o4 * 4 + 0] = fmaf(w.x, yv0, acc0[o4 * 4 + 0]);
                acc0[o4 * 4 + 1] = fmaf(w.y, yv0, acc0[o4 * 4 + 1]);
                acc0[o4 * 4 + 2] = fmaf(w.z, yv0, acc0[o4 * 4 + 2]);
                acc0[o4 * 4 + 3] = fmaf(w.w, yv0, acc0[o4 * 4 + 3]);
                acc1[o4 * 4 + 0] = fmaf(w.x, yv1, acc1[o4 * 4 + 0]);
                acc1[o4 * 4 + 1] = fmaf(w.y, yv1, acc1[o4 * 4 + 1]);
                acc1[o4 * 4 + 2] = fmaf(w.z, yv1, acc1[o4 * 4 + 2]);
                acc1[o4 * 4 + 3] = fmaf(w.w, yv1, acc1[o4 * 4 + 3]);
            }
        }
    }
    // write 1x1 result to sm_q (consecutive px per lane -> conflict-free)
#pragma unroll
    for (int o = 0; o < 32; ++o) {
        sm_q[o * 324 + tid] = acc0[o];
        if (p2) sm_q[o * 324 + 256 + tid] = acc1[o];
    }
    __syncthreads();
    // Phase B: depthwise 3x3 from LDS. thread = 1 output pixel, 32 channels.
    int row = tid >> 4, col = tid & 15;
    float* ob = qkvB + ((size_t)b * C3 + q32 * 32) * HW
                + (ty0 + row) * 128 + tx0 + col;
    for (int ch = 0; ch < 32; ++ch) {
        const float* sq = &sm_q[ch * 324 + row * 18 + col];
        const float* wd = &sm_wd[ch * 9];
        float a = 0.f;
#pragma unroll
        for (int dy = 0; dy < 3; ++dy)
#pragma unroll
            for (int dx = 0; dx < 3; ++dx)
                a = fmaf(wd[dy * 3 + dx], sq[dy * 18 + dx], a);
        ob[(size_t)ch * HW] = a;
    }
}

// ---------------------------------------------------------------------------
// K3: dynamic-kernel fc branch.
// f_conv[b, e*9+o, n] = b_fc[o] + sum_g w_fc[o,g] * qkv_flat[b, n*192 + g*8 + e]
// ---------------------------------------------------------------------------
__global__ __launch_bounds__(256) void k_fc(const float* __restrict__ qkv,
                                            const float* __restrict__ w_fc,
                                            const float* __restrict__ b_fc,
                                            float* __restrict__ fconv) {
    __shared__ float wf[216];
    __shared__ float bf[9];
    int tid = threadIdx.x;
    if (tid < 216) wf[tid] = w_fc[tid];
    if (tid < 9) bf[tid] = b_fc[tid];
    __syncthreads();
    int bid = blockIdx.x;            // 8*512 = 4096
    int b = bid >> 9;
    int rem = bid & 511;             // 32 n per block
    int n = rem * 32 + (tid >> 3);
    int e = tid & 7;
    const float* x = qkv + (size_t)b * C3 * HW + (size_t)n * 192 + e;
    float xe[24];
#pragma unroll
    for (int g = 0; g < 24; ++g) xe[g] = x[g * 8];
    float* ob = fconv + (size_t)b * 72 * HW + n;
#pragma unroll
    for (int o = 0; o < 9; ++o) {
        float acc = bf[o];
#pragma unroll
        for (int g = 0; g < 24; ++g) acc = fmaf(wf[o * 24 + g], xe[g], acc);
        ob[(size_t)(e * 9 + o) * HW] = acc;
    }
}

// ---------------------------------------------------------------------------
// K4: grouped conv 72->64 (groups=8), 3x3 pad 1, + bias. (LDS-tiled)
// ---------------------------------------------------------------------------
#define GST 20
__global__ __launch_bounds__(256) void k_gconv(const float* __restrict__ fconv,
                                               const float* __restrict__ w_dep,
                                               const float* __restrict__ b_dep,
                                               float* __restrict__ outO) {
    __shared__ __align__(16) float sm_in[9 * 18 * GST];  // 12.7 KB
    __shared__ __align__(16) float sm_w[81 * 8];         // [ic*9+kk][o]
    __shared__ float sm_b[8];
    int tid = threadIdx.x;
    int bid = blockIdx.x;          // 8 * 8 * 64 = 4096
    int b = bid >> 9;
    int rem = bid & 511;
    int grp = rem >> 6;            // conv group 0..7
    int tile = rem & 63;
    int ty0 = (tile >> 3) * 16, tx0 = (tile & 7) * 16;
    const float* ibase = fconv + ((size_t)b * 72 + grp * 9) * HW;
    for (int i = tid; i < 9 * 324; i += 256) {
        int c = i / 324;
        int r2 = i - c * 324;
        int r = r2 / 18;
        int q = r2 - r * 18;
        int yy = ty0 + r - 1, xx = tx0 + q - 1;
        sm_in[c * (18 * GST) + r * GST + q] =
            ((unsigned)yy < 128u && (unsigned)xx < 128u)
                ? ibase[(size_t)c * HW + yy * 128 + xx] : 0.f;
    }
    for (int i = tid; i < 648; i += 256) {
        int o = i & 7;
        int ik = i >> 3;           // ic*9+kk, 0..80
        sm_w[i] = w_dep[(size_t)(grp * 8 + o) * 81 + ik];
    }
    if (tid < 8) sm_b[tid] = b_dep[grp * 8 + tid];
    __syncthreads();
    int row = tid >> 4, col = tid & 15;
    float acc[8];
#pragma unroll
    for (int o = 0; o < 8; ++o) acc[o] = sm_b[o];
#pragma unroll
    for (int ic = 0; ic < 9; ++ic) {
        float nb[3][3];
        const float* sc = &sm_in[ic * (18 * GST) + row * GST + col];
#pragma unroll
        for (int r = 0; r < 3; ++r)
#pragma unroll
            for (int q = 0; q < 3; ++q) nb[r][q] = sc[r * GST + q];
        const float* wp = &sm_w[ic * 72];
#pragma unroll
        for (int k = 0; k < 9; ++k) {
            float4 w0 = *(const float4*)(wp + k * 8);
            float4 w1 = *(const float4*)(wp + k * 8 + 4);
            float v = nb[k / 3][k % 3];
            acc[0] = fmaf(w0.x, v, acc[0]);
            acc[1] = fmaf(w0.y, v, acc[1]);
            acc[2] = fmaf(w0.z, v, acc[2]);
            acc[3] = fmaf(w0.w, v, acc[3]);
            acc[4] = fmaf(w1.x, v, acc[4]);
            acc[5] = fmaf(w1.y, v, acc[5]);
            acc[6] = fmaf(w1.z, v, acc[6]);
            acc[7] = fmaf(w1.w, v, acc[7]);
        }
    }
    float* ob = outO + ((size_t)b * 64 + grp * 8) * HW + (ty0 + row) * 128 + tx0 + col;
#pragma unroll
    for (int o = 0; o < 8; ++o) ob[(size_t)o * HW] = acc[o];
}

// ---------------------------------------------------------------------------
// K5b: attention matrix, with Q/K L2-norms fused in.
// ---------------------------------------------------------------------------
__global__ __launch_bounds__(256) void k_attn(const float* __restrict__ qkv,
                                              const float* __restrict__ temperature,
                                              float* __restrict__ attn) {
    __shared__ float red[4][64];
    __shared__ float redq[4][8];
    __shared__ float redk[4][8];
    __shared__ float sm_inv[16];
    __shared__ float lg[64];
    int bid = blockIdx.x;  // 8*8 = 64
    int b = bid >> 3, h = bid & 7;
    int tid = threadIdx.x;
    const float* Q = qkv + ((size_t)b * C3 + h * 8) * HW;
    const float* K = Q + (size_t)64 * HW;
    float acc[64], qs[8], ks[8];
#pragma unroll
    for (int j = 0; j < 64; ++j) acc[j] = 0.f;
#pragma unroll
    for (int d = 0; d < 8; ++d) { qs[d] = 0.f; ks[d] = 0.f; }
    for (int i = tid; i < HW; i += 256) {
        float qv[8], kv[8];
#pragma unroll
        for (int d = 0; d < 8; ++d) {
            qv[d] = Q[(size_t)d * HW + i];
            kv[d] = K[(size_t)d * HW + i];
        }
#pragma unroll
        for (int d = 0; d < 8; ++d) {
            qs[d] = fmaf(qv[d], qv[d], qs[d]);
            ks[d] = fmaf(kv[d], kv[d], ks[d]);
        }
#pragma unroll
        for (int c = 0; c < 8; ++c)
#pragma unroll
            for (int d = 0; d < 8; ++d)
                acc[c * 8 + d] = fmaf(qv[c], kv[d], acc[c * 8 + d]);
    }
#pragma unroll
    for (int j = 0; j < 64; ++j) {
#pragma unroll
        for (int off = 32; off; off >>= 1) acc[j] += __shfl_down(acc[j], off, 64);
    }
#pragma unroll
    for (int d = 0; d < 8; ++d) {
#pragma unroll
        for (int off = 32; off; off >>= 1) {
            qs[d] += __shfl_down(qs[d], off, 64);
            ks[d] += __shfl_down(ks[d], off, 64);
        }
    }
    int lane = tid & 63, wv = tid >> 6;
    if (lane == 0) {
#pragma unroll
        for (int j = 0; j < 64; ++j) red[wv][j] = acc[j];
#pragma unroll
        for (int d = 0; d < 8; ++d) { redq[wv][d] = qs[d]; redk[wv][d] = ks[d]; }
    }
    __syncthreads();
    if (tid < 16) {
        int d = tid & 7;
        float s = (tid < 8) ? (redq[0][d] + redq[1][d] + redq[2][d] + redq[3][d])
                            : (redk[0][d] + redk[1][d] + redk[2][d] + redk[3][d]);
        sm_inv[tid] = 1.f / fmaxf(sqrtf(s), 1e-12f);
    }
    __syncthreads();
    if (tid < 64) {
        float s = red[0][tid] + red[1][tid] + red[2][tid] + red[3][tid];
        int c = tid >> 3, d = tid & 7;
        lg[tid] = s * sm_inv[c] * sm_inv[8 + d] * temperature[h];
    }
    __syncthreads();
    if (tid < 8) {
        int c = tid;
        float m = lg[c * 8];
#pragma unroll
        for (int d = 1; d < 8; ++d) m = fmaxf(m, lg[c * 8 + d]);
        float ssum = 0.f, ex[8];
#pragma unroll
        for (int d = 0; d < 8; ++d) { ex[d] = expf(lg[c * 8 + d] - m); ssum += ex[d]; }
        float inv = 1.f / ssum;
#pragma unroll
        for (int d = 0; d < 8; ++d)
            attn[((size_t)(b * 8 + h) * 8 + c) * 8 + d] = ex[d] * inv;
    }
}

// ---------------------------------------------------------------------------
// K5c: out = attn.V per head, then 1x1 proj, added in-place into outO.
// ---------------------------------------------------------------------------
__global__ __launch_bounds__(256) void k_av_proj(const float* __restrict__ qkv,
                                                 const float* __restrict__ attn,
                                                 const float* __restrict__ w_proj,
                                                 float* __restrict__ outO) {
    __shared__ float at[512];
    __shared__ float wp[4096];  // [c][o]
    int tid = threadIdx.x;
    int bid = blockIdx.x;  // 8*64 = 512
    int b = bid >> 6, tile = bid & 63;
    for (int i = tid; i < 512; i += 256) at[i] = attn[b * 512 + i];
    for (int i = tid; i < 4096; i += 256) {
        int c = i >> 6, o = i & 63;
        wp[i] = w_proj[o * 64 + c];
    }
    __syncthreads();
    int p = tile * 256 + tid;
    const float* vb = qkv + ((size_t)b * C3 + 128) * HW + p;
    float av[64];
#pragma unroll
    for (int h = 0; h < 8; ++h) {
        float vv[8];
#pragma unroll
        for (int d = 0; d < 8; ++d) vv[d] = vb[(size_t)(h * 8 + d) * HW];
#pragma unroll
        for (int ci = 0; ci < 8; ++ci) {
            float s = 0.f;
#pragma unroll
            for (int d = 0; d < 8; ++d) s = fmaf(at[(h * 8 + ci) * 8 + d], vv[d], s);
            av[h * 8 + ci] = s;
        }
    }
    float* ob = outO + (size_t)b * 64 * HW + p;
    float acc[64];
#pragma unroll
    for (int o = 0; o < 64; ++o) acc[o] = ob[(size_t)o * HW];
    for (int c = 0; c < 64; ++c) {
        float a = av[c];
        const float* wr = &wp[c * 64];
#pragma unroll
        for (int o = 0; o < 64; ++o) acc[o] = fmaf(wr[o], a, acc[o]);
    }
#pragma unroll
    for (int o = 0; o < 64; ++o) ob[(size_t)o * HW] = acc[o];
}

// ---------------------------------------------------------------------------
// K6: fuse 3x3 conv 64->64 + BN + residual ReLU.  (LDS-tiled, 32 oc/block
// for occupancy: r4 showed grid=512 capped occupancy at 20%/2 blocks/CU)
// Block: 16x16 pixel tile x 32 out-channels; c looped in 8 chunks of 8.
// Thread = 4 rows x 1 col x 8 o -> 32 acc; 288 FMA per c vs ~36 LDS reads.
// ---------------------------------------------------------------------------
#define ST 20  // padded row stride for input tile
__global__ __launch_bounds__(256) void k_fuse(const float* __restrict__ outO,
                                              const float* __restrict__ w_fuse,
                                              const float* __restrict__ bn_gamma,
                                              const float* __restrict__ bn_beta,
                                              const float* __restrict__ bn_mean,
                                              const float* __restrict__ bn_var,
                                              const float* __restrict__ y,
                                              float* __restrict__ dout) {
    __shared__ __align__(16) float sm_in[8 * 18 * ST];   // 11.25 KB
    __shared__ __align__(16) float sm_w[8 * 9 * 32];     // 9 KB, [c][k][o32]
    __shared__ float sm_sc[64];
    __shared__ float sm_sb[64];
    int tid = threadIdx.x;
    int bid = blockIdx.x;          // 8b * 2ob * 64tile = 1024
    int b = bid >> 7;
    int rem = bid & 127;
    int ob32 = rem >> 6;           // 32-channel output half
    int tile = rem & 63;
    int ty0 = (tile >> 3) * 16, tx0 = (tile & 7) * 16;

    if (tid < 64) {
        float sc = bn_gamma[tid] * rsqrtf(bn_var[tid] + 1e-5f);
        sm_sc[tid] = sc;
        sm_sb[tid] = bn_beta[tid] - bn_mean[tid] * sc;
    }

    int osub = tid >> 6;           // wave id 0..3 -> o0 = osub*8
    int o0 = osub * 8;
    int lane = tid & 63;
    int col = lane & 15;
    int rowg = lane >> 4;
    int r0 = rowg * 4;

    const float* ib = outO + (size_t)b * 64 * HW;
    float acc[4][8];
#pragma unroll
    for (int p = 0; p < 4; ++p)
#pragma unroll
        for (int o = 0; o < 8; ++o) acc[p][o] = 0.f;

    for (int ch = 0; ch < 8; ++ch) {
        int c0 = ch * 8;
        __syncthreads();
        for (int i = tid; i < 8 * 18 * 18; i += 256) {
            int c = i / 324;
            int rem2 = i - c * 324;
            int r = rem2 / 18;
            int q = rem2 - r * 18;
            int yy = ty0 + r - 1;
            int xx = tx0 + q - 1;
            float v = ((unsigned)yy < 128u && (unsigned)xx < 128u)
                          ? ib[(size_t)(c0 + c) * HW + yy * 128 + xx] : 0.f;
            sm_in[c * (18 * ST) + r * ST + q] = v;
        }
        for (int i = tid; i < 8 * 9 * 32; i += 256) {
            int o = i & 31;
            int kk = (i >> 5) % 9;
            int c = i / 288;
            sm_w[(c * 9 + kk) * 32 + o] =
                w_fuse[((size_t)(ob32 * 32 + o) * 64 + (c0 + c)) * 9 + kk];
        }
        __syncthreads();
        for (int cc = 0; cc < 8; ++cc) {
            float nb[6][3];
            const float* sin_c = &sm_in[cc * (18 * ST)];
#pragma unroll
            for (int r = 0; r < 6; ++r)
#pragma unroll
                for (int q = 0; q < 3; ++q)
                    nb[r][q] = sin_c[(r0 + r) * ST + col + q];
            const float* wc = &sm_w[cc * 288 + o0];
#pragma unroll
            for (int k = 0; k < 9; ++k) {
                int ky = k / 3, kx = k % 3;
                float4 w0 = *(const float4*)(wc + k * 32);
                float4 w1 = *(const float4*)(wc + k * 32 + 4);
#pragma unroll
                for (int p = 0; p < 4; ++p) {
                    float v = nb[p + ky][kx];
                    acc[p][0] = fmaf(w0.x, v, acc[p][0]);
                    acc[p][1] = fmaf(w0.y, v, acc[p][1]);
                    acc[p][2] = fmaf(w0.z, v, acc[p][2]);
                    acc[p][3] = fmaf(w0.w, v, acc[p][3]);
                    acc[p][4] = fmaf(w1.x, v, acc[p][4]);
                    acc[p][5] = fmaf(w1.y, v, acc[p][5]);
                    acc[p][6] = fmaf(w1.z, v, acc[p][6]);
                    acc[p][7] = fmaf(w1.w, v, acc[p][7]);
                }
            }
        }
    }
    // epilogue: BN + residual + ReLU
#pragma unroll
    for (int o = 0; o < 8; ++o) {
        int og = ob32 * 32 + o0 + o;
        float sc = sm_sc[og], sb = sm_sb[og];
#pragma unroll
        for (int p = 0; p < 4; ++p) {
            int pyy = ty0 + r0 + p;
            int pxx = tx0 + col;
            size_t idx = ((size_t)b * 64 + og) * HW + pyy * 128 + pxx;
            float v = acc[p][o] * sc + sb + y[idx];
            dout[idx] = fmaxf(v, 0.f);
        }
    }
}

// ---------------------------------------------------------------------------
extern "C" void kernel_launch(void* const* d_in, const int* in_sizes, int n_in,
                              void* d_out, int out_size, void* d_ws, size_t ws_size,
                              hipStream_t stream) {
    const float* y           = (const float*)d_in[0];
    const float* w_qkv       = (const float*)d_in[1];
    const float* w_dw        = (const float*)d_in[2];
    const float* w_proj      = (const float*)d_in[3];
    const float* w_fc        = (const float*)d_in[4];
    const float* b_fc        = (const float*)d_in[5];
    const float* w_dep       = (const float*)d_in[6];
    const float* b_dep       = (const float*)d_in[7];
    const float* temperature = (const float*)d_in[8];
    const float* w_fuse      = (const float*)d_in[9];
    const float* bn_gamma    = (const float*)d_in[10];
    const float* bn_beta     = (const float*)d_in[11];
    const float* bn_mean     = (const float*)d_in[12];
    const float* bn_var      = (const float*)d_in[13];
    float* out = (float*)d_out;

    // Per-group scratch (8 batches/group), total ~172 MB:
    float* ws    = (float*)d_ws;
    float* qkvB  = ws;               // [8][192][16384] = 25,165,824 f
    float* bufT  = ws + 25165824;    // fconv, 9,437,184 f
    float* bufO  = ws + 34603008;    // out_conv -> output, 8,388,608 f
    float* attn  = ws + 42992640;    // 4096 f
    (void)in_sizes; (void)n_in; (void)out_size; (void)ws_size;

    for (int g = 0; g < 2; ++g) {
        const float* yg = y + (size_t)g * 8 * CC * HW;
        float* outg = out + (size_t)g * 8 * CC * HW;
        k_qkvdw<<<3072, 256, 0, stream>>>(yg, w_qkv, w_dw, qkvB);
        k_fc<<<4096, 256, 0, stream>>>(qkvB, w_fc, b_fc, bufT);
        k_gconv<<<4096, 256, 0, stream>>>(bufT, w_dep, b_dep, bufO);
        k_attn<<<64, 256, 0, stream>>>(qkvB, temperature, attn);
        k_av_proj<<<512, 256, 0, stream>>>(qkvB, attn, w_proj, bufO);
        k_fuse<<<1024, 256, 0, stream>>>(bufO, w_fuse, bn_gamma, bn_beta,
                                         bn_mean, bn_var, yg, outg);
    }
}

// Round 8
// 1024.934 us; speedup vs baseline: 1.9681x; 1.9681x over previous
//
#include <hip/hip_runtime.h>
#include <hip/hip_bf16.h>

// Problem constants (fixed by reference)
#define BN 16
#define CC 64
#define HH 128
#define WW 128
#define HW 16384
#define C3 192
#define NHEADS 8

// NOTE: launcher processes batches in 2 groups of 8 (workspace ~172 MB).
// r6 lesson: fused qkv+dw collapsed occupancy (61KB LDS, 172 VGPR -> 12%);
// reverted to the r4-measured split chain (~315us/total for the pair).

// ---------------------------------------------------------------------------
// K1: qkv 1x1 conv, one 64-output-channel chunk. (r4 measured-good)
// ---------------------------------------------------------------------------
__global__ __launch_bounds__(256) void k_qkv1(const float* __restrict__ y,
                                              const float* __restrict__ w_qkv,
                                              float* __restrict__ out, int chunk) {
    __shared__ float ws[64 * 64];  // [c][o]
    int tid = threadIdx.x;
    for (int i = tid; i < 4096; i += 256) {
        int c = i >> 6, o = i & 63;
        ws[i] = w_qkv[(chunk * 64 + o) * 64 + c];
    }
    __syncthreads();
    int bid = blockIdx.x;           // 8 * (HW/256) = 512
    int b = bid >> 6;
    int ptile = bid & 63;
    int pxg = tid & 127;            // 128 pixel-pairs
    int osub = tid >> 7;            // 0..1 -> o base osub*32
    int p0 = ptile * 256 + pxg * 2;
    const float* yb = y + (size_t)b * CC * HW + p0;
    float acc0[32];
    float acc1[32];
#pragma unroll
    for (int o = 0; o < 32; ++o) { acc0[o] = 0.f; acc1[o] = 0.f; }
    for (int c = 0; c < 64; ++c) {
        float2 yv = *(const float2*)(yb + (size_t)c * HW);
        const float* wr = &ws[c * 64 + osub * 32];
#pragma unroll
        for (int o = 0; o < 32; ++o) {
            float w = wr[o];
            acc0[o] = fmaf(w, yv.x, acc0[o]);
            acc1[o] = fmaf(w, yv.y, acc1[o]);
        }
    }
    float* ob = out + (size_t)b * 64 * HW + (size_t)(osub * 32) * HW + p0;
#pragma unroll
    for (int o = 0; o < 32; ++o) {
        *(float2*)(ob + (size_t)o * HW) = make_float2(acc0[o], acc1[o]);
    }
}

// ---------------------------------------------------------------------------
// K2: depthwise 3x3 (pad 1) on one 64-channel chunk. (r4 measured-good)
// ---------------------------------------------------------------------------
__global__ __launch_bounds__(256) void k_dw(const float* __restrict__ in,
                                            const float* __restrict__ w_dw,
                                            float* __restrict__ out, int chunk) {
    int bid = blockIdx.x;           // 8*64*32 = 16384
    int tid = threadIdx.x;
    int b = bid >> 11;
    int rem = bid & 2047;
    int ch = rem >> 5;
    int tile = rem & 31;
    int pp = tile * 512 + tid * 2;
    int py = pp >> 7, px = pp & 127;
    const float* ib = in + ((size_t)b * 64 + ch) * HW;
    const float* wr = w_dw + (chunk * 64 + ch) * 9;
    float w[9];
#pragma unroll
    for (int i = 0; i < 9; ++i) w[i] = wr[i];
    float a0 = 0.f, a1 = 0.f;
#pragma unroll
    for (int ky = 0; ky < 3; ++ky) {
        int yy = py + ky - 1;
        bool yok = (unsigned)yy < 128u;
#pragma unroll
        for (int kx = 0; kx < 4; ++kx) {
            int xx = px + kx - 1;
            bool ok = yok && ((unsigned)xx < 128u);
            float v = ok ? ib[yy * 128 + xx] : 0.f;
            if (kx < 3) a0 = fmaf(w[ky * 3 + kx], v, a0);
            if (kx > 0) a1 = fmaf(w[ky * 3 + kx - 1], v, a1);
        }
    }
    *(float2*)(out + ((size_t)b * C3 + chunk * 64 + ch) * HW + pp) = make_float2(a0, a1);
}

// ---------------------------------------------------------------------------
// K3: dynamic-kernel fc branch.  (REWRITTEN: LDS-staged coalesced reads)
// f_conv[b, e*9+o, n] = b_fc[o] + sum_g w_fc[o,g] * qkv_flat[b, n*192 + g*8 + e]
// Block = 32 pixels: stage 32x192 floats (contiguous -> float4 coalesced)
// into LDS stride 193 (2-way bank alias only). Thread = (e = tid>>5, n=tid&31).
// ---------------------------------------------------------------------------
__global__ __launch_bounds__(256) void k_fc(const float* __restrict__ qkv,
                                            const float* __restrict__ w_fc,
                                            const float* __restrict__ b_fc,
                                            float* __restrict__ fconv) {
    __shared__ float wf[216];
    __shared__ float bf[9];
    __shared__ float sx[32 * 193];   // 24.7 KB
    int tid = threadIdx.x;
    if (tid < 216) wf[tid] = w_fc[tid];
    if (tid < 9) bf[tid] = b_fc[tid];
    int bid = blockIdx.x;            // 8b * 512 = 4096
    int b = bid >> 9;
    int n0 = (bid & 511) * 32;
    const float* src = qkv + (size_t)b * C3 * HW + (size_t)n0 * 192;
    for (int f4 = tid; f4 < 1536; f4 += 256) {
        int f = f4 * 4;
        int nl = f / 192;
        int r = f - nl * 192;
        float4 v = *(const float4*)(src + f);
        float* d = &sx[nl * 193 + r];
        d[0] = v.x; d[1] = v.y; d[2] = v.z; d[3] = v.w;
    }
    __syncthreads();
    int e = tid >> 5, n = tid & 31;
    const float* xr = &sx[n * 193 + e];
    float acc[9];
#pragma unroll
    for (int o = 0; o < 9; ++o) acc[o] = bf[o];
#pragma unroll
    for (int g = 0; g < 24; ++g) {
        float xv = xr[g * 8];
#pragma unroll
        for (int o = 0; o < 9; ++o) acc[o] = fmaf(wf[o * 24 + g], xv, acc[o]);
    }
    float* ob = fconv + (size_t)b * 72 * HW + n0 + n;
#pragma unroll
    for (int o = 0; o < 9; ++o) ob[(size_t)(e * 9 + o) * HW] = acc[o];
}

// ---------------------------------------------------------------------------
// K4: grouped conv 72->64 (groups=8), 3x3 pad 1, + bias. (r4 measured-good)
// ---------------------------------------------------------------------------
#define GST 20
__global__ __launch_bounds__(256) void k_gconv(const float* __restrict__ fconv,
                                               const float* __restrict__ w_dep,
                                               const float* __restrict__ b_dep,
                                               float* __restrict__ outO) {
    __shared__ __align__(16) float sm_in[9 * 18 * GST];  // 12.7 KB
    __shared__ __align__(16) float sm_w[81 * 8];         // [ic*9+kk][o]
    __shared__ float sm_b[8];
    int tid = threadIdx.x;
    int bid = blockIdx.x;          // 8 * 8 * 64 = 4096
    int b = bid >> 9;
    int rem = bid & 511;
    int grp = rem >> 6;            // conv group 0..7
    int tile = rem & 63;
    int ty0 = (tile >> 3) * 16, tx0 = (tile & 7) * 16;
    const float* ibase = fconv + ((size_t)b * 72 + grp * 9) * HW;
    for (int i = tid; i < 9 * 324; i += 256) {
        int c = i / 324;
        int r2 = i - c * 324;
        int r = r2 / 18;
        int q = r2 - r * 18;
        int yy = ty0 + r - 1, xx = tx0 + q - 1;
        sm_in[c * (18 * GST) + r * GST + q] =
            ((unsigned)yy < 128u && (unsigned)xx < 128u)
                ? ibase[(size_t)c * HW + yy * 128 + xx] : 0.f;
    }
    for (int i = tid; i < 648; i += 256) {
        int o = i & 7;
        int ik = i >> 3;           // ic*9+kk, 0..80
        sm_w[i] = w_dep[(size_t)(grp * 8 + o) * 81 + ik];
    }
    if (tid < 8) sm_b[tid] = b_dep[grp * 8 + tid];
    __syncthreads();
    int row = tid >> 4, col = tid & 15;
    float acc[8];
#pragma unroll
    for (int o = 0; o < 8; ++o) acc[o] = sm_b[o];
#pragma unroll
    for (int ic = 0; ic < 9; ++ic) {
        float nb[3][3];
        const float* sc = &sm_in[ic * (18 * GST) + row * GST + col];
#pragma unroll
        for (int r = 0; r < 3; ++r)
#pragma unroll
            for (int q = 0; q < 3; ++q) nb[r][q] = sc[r * GST + q];
        const float* wp = &sm_w[ic * 72];
#pragma unroll
        for (int k = 0; k < 9; ++k) {
            float4 w0 = *(const float4*)(wp + k * 8);
            float4 w1 = *(const float4*)(wp + k * 8 + 4);
            float v = nb[k / 3][k % 3];
            acc[0] = fmaf(w0.x, v, acc[0]);
            acc[1] = fmaf(w0.y, v, acc[1]);
            acc[2] = fmaf(w0.z, v, acc[2]);
            acc[3] = fmaf(w0.w, v, acc[3]);
            acc[4] = fmaf(w1.x, v, acc[4]);
            acc[5] = fmaf(w1.y, v, acc[5]);
            acc[6] = fmaf(w1.z, v, acc[6]);
            acc[7] = fmaf(w1.w, v, acc[7]);
        }
    }
    float* ob = outO + ((size_t)b * 64 + grp * 8) * HW + (ty0 + row) * 128 + tx0 + col;
#pragma unroll
    for (int o = 0; o < 8; ++o) ob[(size_t)o * HW] = acc[o];
}

// ---------------------------------------------------------------------------
// K5b-1: attention partials. Grid = (b,h,seg): 4 spatial segments of HW/4.
// Writes 80 raw sums (64 logits + 8 q-sumsq + 8 k-sumsq) per (b,h,seg).
// (r6: 64-block version used 25% of CUs; this uses 256 blocks.)
// ---------------------------------------------------------------------------
__global__ __launch_bounds__(256) void k_attn_p(const float* __restrict__ qkv,
                                                float* __restrict__ partial) {
    __shared__ float red[4][64];
    __shared__ float redq[4][8];
    __shared__ float redk[4][8];
    int bid = blockIdx.x;  // 8b*8h*4seg = 256
    int b = bid >> 5, h = (bid >> 2) & 7, seg = bid & 3;
    int tid = threadIdx.x;
    const float* Q = qkv + ((size_t)b * C3 + h * 8) * HW;
    const float* K = Q + (size_t)64 * HW;
    float acc[64], qs[8], ks[8];
#pragma unroll
    for (int j = 0; j < 64; ++j) acc[j] = 0.f;
#pragma unroll
    for (int d = 0; d < 8; ++d) { qs[d] = 0.f; ks[d] = 0.f; }
    int iend = (seg + 1) * 4096;
    for (int i = seg * 4096 + tid; i < iend; i += 256) {
        float qv[8], kv[8];
#pragma unroll
        for (int d = 0; d < 8; ++d) {
            qv[d] = Q[(size_t)d * HW + i];
            kv[d] = K[(size_t)d * HW + i];
        }
#pragma unroll
        for (int d = 0; d < 8; ++d) {
            qs[d] = fmaf(qv[d], qv[d], qs[d]);
            ks[d] = fmaf(kv[d], kv[d], ks[d]);
        }
#pragma unroll
        for (int c = 0; c < 8; ++c)
#pragma unroll
            for (int d = 0; d < 8; ++d)
                acc[c * 8 + d] = fmaf(qv[c], kv[d], acc[c * 8 + d]);
    }
#pragma unroll
    for (int j = 0; j < 64; ++j) {
#pragma unroll
        for (int off = 32; off; off >>= 1) acc[j] += __shfl_down(acc[j], off, 64);
    }
#pragma unroll
    for (int d = 0; d < 8; ++d) {
#pragma unroll
        for (int off = 32; off; off >>= 1) {
            qs[d] += __shfl_down(qs[d], off, 64);
            ks[d] += __shfl_down(ks[d], off, 64);
        }
    }
    int lane = tid & 63, wv = tid >> 6;
    if (lane == 0) {
#pragma unroll
        for (int j = 0; j < 64; ++j) red[wv][j] = acc[j];
#pragma unroll
        for (int d = 0; d < 8; ++d) { redq[wv][d] = qs[d]; redk[wv][d] = ks[d]; }
    }
    __syncthreads();
    float* outp = partial + (size_t)bid * 80;
    if (tid < 64) {
        outp[tid] = red[0][tid] + red[1][tid] + red[2][tid] + red[3][tid];
    } else if (tid < 72) {
        int d = tid - 64;
        outp[64 + d] = redq[0][d] + redq[1][d] + redq[2][d] + redq[3][d];
    } else if (tid < 80) {
        int d = tid - 72;
        outp[72 + d] = redk[0][d] + redk[1][d] + redk[2][d] + redk[3][d];
    }
}

// ---------------------------------------------------------------------------
// K5b-2: reduce partials, L2-normalize, temperature, softmax -> attn.
// ---------------------------------------------------------------------------
__global__ __launch_bounds__(256) void k_attn_f(const float* __restrict__ partial,
                                                const float* __restrict__ temperature,
                                                float* __restrict__ attn) {
    __shared__ float sm[80];
    __shared__ float lg[64];
    int bh = blockIdx.x;  // 64
    int h = bh & 7;
    int tid = threadIdx.x;
    if (tid < 80) {
        const float* pp = partial + (size_t)bh * 4 * 80 + tid;
        sm[tid] = pp[0] + pp[80] + pp[160] + pp[240];
    }
    __syncthreads();
    if (tid < 64) {
        int c = tid >> 3, d = tid & 7;
        float invq = 1.f / fmaxf(sqrtf(sm[64 + c]), 1e-12f);
        float invk = 1.f / fmaxf(sqrtf(sm[72 + d]), 1e-12f);
        lg[tid] = sm[tid] * invq * invk * temperature[h];
    }
    __syncthreads();
    if (tid < 8) {
        int c = tid;
        float m = lg[c * 8];
#pragma unroll
        for (int d = 1; d < 8; ++d) m = fmaxf(m, lg[c * 8 + d]);
        float ssum = 0.f, ex[8];
#pragma unroll
        for (int d = 0; d < 8; ++d) { ex[d] = expf(lg[c * 8 + d] - m); ssum += ex[d]; }
        float inv = 1.f / ssum;
#pragma unroll
        for (int d = 0; d < 8; ++d)
            attn[(size_t)bh * 64 + c * 8 + d] = ex[d] * inv;
    }
}

// ---------------------------------------------------------------------------
// K5c: out = attn.V per head, then 1x1 proj, added in-place into outO.
// ---------------------------------------------------------------------------
__global__ __launch_bounds__(256) void k_av_proj(const float* __restrict__ qkv,
                                                 const float* __restrict__ attn,
                                                 const float* __restrict__ w_proj,
                                                 float* __restrict__ outO) {
    __shared__ float at[512];
    __shared__ float wp[4096];  // [c][o]
    int tid = threadIdx.x;
    int bid = blockIdx.x;  // 8*64 = 512
    int b = bid >> 6, tile = bid & 63;
    for (int i = tid; i < 512; i += 256) at[i] = attn[b * 512 + i];
    for (int i = tid; i < 4096; i += 256) {
        int c = i >> 6, o = i & 63;
        wp[i] = w_proj[o * 64 + c];
    }
    __syncthreads();
    int p = tile * 256 + tid;
    const float* vb = qkv + ((size_t)b * C3 + 128) * HW + p;
    float av[64];
#pragma unroll
    for (int h = 0; h < 8; ++h) {
        float vv[8];
#pragma unroll
        for (int d = 0; d < 8; ++d) vv[d] = vb[(size_t)(h * 8 + d) * HW];
#pragma unroll
        for (int ci = 0; ci < 8; ++ci) {
            float s = 0.f;
#pragma unroll
            for (int d = 0; d < 8; ++d) s = fmaf(at[(h * 8 + ci) * 8 + d], vv[d], s);
            av[h * 8 + ci] = s;
        }
    }
    float* ob = outO + (size_t)b * 64 * HW + p;
    float acc[64];
#pragma unroll
    for (int o = 0; o < 64; ++o) acc[o] = ob[(size_t)o * HW];
    for (int c = 0; c < 64; ++c) {
        float a = av[c];
        const float* wr = &wp[c * 64];
#pragma unroll
        for (int o = 0; o < 64; ++o) acc[o] = fmaf(wr[o], a, acc[o]);
    }
#pragma unroll
    for (int o = 0; o < 64; ++o) ob[(size_t)o * HW] = acc[o];
}

// ---------------------------------------------------------------------------
// K6: fuse 3x3 conv 64->64 + BN + residual ReLU.  (LDS-tiled, 32 oc/block)
// ---------------------------------------------------------------------------
#define ST 20  // padded row stride for input tile
__global__ __launch_bounds__(256) void k_fuse(const float* __restrict__ outO,
                                              const float* __restrict__ w_fuse,
                                              const float* __restrict__ bn_gamma,
                                              const float* __restrict__ bn_beta,
                                              const float* __restrict__ bn_mean,
                                              const float* __restrict__ bn_var,
                                              const float* __restrict__ y,
                                              float* __restrict__ dout) {
    __shared__ __align__(16) float sm_in[8 * 18 * ST];   // 11.25 KB
    __shared__ __align__(16) float sm_w[8 * 9 * 32];     // 9 KB, [c][k][o32]
    __shared__ float sm_sc[64];
    __shared__ float sm_sb[64];
    int tid = threadIdx.x;
    int bid = blockIdx.x;          // 8b * 2ob * 64tile = 1024
    int b = bid >> 7;
    int rem = bid & 127;
    int ob32 = rem >> 6;           // 32-channel output half
    int tile = rem & 63;
    int ty0 = (tile >> 3) * 16, tx0 = (tile & 7) * 16;

    if (tid < 64) {
        float sc = bn_gamma[tid] * rsqrtf(bn_var[tid] + 1e-5f);
        sm_sc[tid] = sc;
        sm_sb[tid] = bn_beta[tid] - bn_mean[tid] * sc;
    }

    int osub = tid >> 6;           // wave id 0..3 -> o0 = osub*8
    int o0 = osub * 8;
    int lane = tid & 63;
    int col = lane & 15;
    int rowg = lane >> 4;
    int r0 = rowg * 4;

    const float* ib = outO + (size_t)b * 64 * HW;
    float acc[4][8];
#pragma unroll
    for (int p = 0; p < 4; ++p)
#pragma unroll
        for (int o = 0; o < 8; ++o) acc[p][o] = 0.f;

    for (int ch = 0; ch < 8; ++ch) {
        int c0 = ch * 8;
        __syncthreads();
        for (int i = tid; i < 8 * 18 * 18; i += 256) {
            int c = i / 324;
            int rem2 = i - c * 324;
            int r = rem2 / 18;
            int q = rem2 - r * 18;
            int yy = ty0 + r - 1;
            int xx = tx0 + q - 1;
            float v = ((unsigned)yy < 128u && (unsigned)xx < 128u)
                          ? ib[(size_t)(c0 + c) * HW + yy * 128 + xx] : 0.f;
            sm_in[c * (18 * ST) + r * ST + q] = v;
        }
        for (int i = tid; i < 8 * 9 * 32; i += 256) {
            int o = i & 31;
            int kk = (i >> 5) % 9;
            int c = i / 288;
            sm_w[(c * 9 + kk) * 32 + o] =
                w_fuse[((size_t)(ob32 * 32 + o) * 64 + (c0 + c)) * 9 + kk];
        }
        __syncthreads();
        for (int cc = 0; cc < 8; ++cc) {
            float nb[6][3];
            const float* sin_c = &sm_in[cc * (18 * ST)];
#pragma unroll
            for (int r = 0; r < 6; ++r)
#pragma unroll
                for (int q = 0; q < 3; ++q)
                    nb[r][q] = sin_c[(r0 + r) * ST + col + q];
            const float* wc = &sm_w[cc * 288 + o0];
#pragma unroll
            for (int k = 0; k < 9; ++k) {
                int ky = k / 3, kx = k % 3;
                float4 w0 = *(const float4*)(wc + k * 32);
                float4 w1 = *(const float4*)(wc + k * 32 + 4);
#pragma unroll
                for (int p = 0; p < 4; ++p) {
                    float v = nb[p + ky][kx];
                    acc[p][0] = fmaf(w0.x, v, acc[p][0]);
                    acc[p][1] = fmaf(w0.y, v, acc[p][1]);
                    acc[p][2] = fmaf(w0.z, v, acc[p][2]);
                    acc[p][3] = fmaf(w0.w, v, acc[p][3]);
                    acc[p][4] = fmaf(w1.x, v, acc[p][4]);
                    acc[p][5] = fmaf(w1.y, v, acc[p][5]);
                    acc[p][6] = fmaf(w1.z, v, acc[p][6]);
                    acc[p][7] = fmaf(w1.w, v, acc[p][7]);
                }
            }
        }
    }
    // epilogue: BN + residual + ReLU
#pragma unroll
    for (int o = 0; o < 8; ++o) {
        int og = ob32 * 32 + o0 + o;
        float sc = sm_sc[og], sb = sm_sb[og];
#pragma unroll
        for (int p = 0; p < 4; ++p) {
            int pyy = ty0 + r0 + p;
            int pxx = tx0 + col;
            size_t idx = ((size_t)b * 64 + og) * HW + pyy * 128 + pxx;
            float v = acc[p][o] * sc + sb + y[idx];
            dout[idx] = fmaxf(v, 0.f);
        }
    }
}

// ---------------------------------------------------------------------------
extern "C" void kernel_launch(void* const* d_in, const int* in_sizes, int n_in,
                              void* d_out, int out_size, void* d_ws, size_t ws_size,
                              hipStream_t stream) {
    const float* y           = (const float*)d_in[0];
    const float* w_qkv       = (const float*)d_in[1];
    const float* w_dw        = (const float*)d_in[2];
    const float* w_proj      = (const float*)d_in[3];
    const float* w_fc        = (const float*)d_in[4];
    const float* b_fc        = (const float*)d_in[5];
    const float* w_dep       = (const float*)d_in[6];
    const float* b_dep       = (const float*)d_in[7];
    const float* temperature = (const float*)d_in[8];
    const float* w_fuse      = (const float*)d_in[9];
    const float* bn_gamma    = (const float*)d_in[10];
    const float* bn_beta     = (const float*)d_in[11];
    const float* bn_mean     = (const float*)d_in[12];
    const float* bn_var      = (const float*)d_in[13];
    float* out = (float*)d_out;

    // Per-group scratch (8 batches/group), total ~172 MB:
    float* ws    = (float*)d_ws;
    float* qkvB  = ws;               // [8][192][16384] = 25,165,824 f
    float* bufT  = ws + 25165824;    // qkv1 tmp (8.4M f) / fconv (9.4M f)
    float* bufO  = ws + 34603008;    // out_conv -> output, 8,388,608 f
    float* attn  = ws + 42992640;    // 4096 f
    float* attnP = ws + 42996736;    // 64*4*80 = 20480 f
    (void)in_sizes; (void)n_in; (void)out_size; (void)ws_size;

    for (int g = 0; g < 2; ++g) {
        const float* yg = y + (size_t)g * 8 * CC * HW;
        float* outg = out + (size_t)g * 8 * CC * HW;
        for (int chunk = 0; chunk < 3; ++chunk) {
            k_qkv1<<<512, 256, 0, stream>>>(yg, w_qkv, bufT, chunk);
            k_dw<<<16384, 256, 0, stream>>>(bufT, w_dw, qkvB, chunk);
        }
        k_fc<<<4096, 256, 0, stream>>>(qkvB, w_fc, b_fc, bufT);
        k_gconv<<<4096, 256, 0, stream>>>(bufT, w_dep, b_dep, bufO);
        k_attn_p<<<256, 256, 0, stream>>>(qkvB, attnP);
        k_attn_f<<<64, 256, 0, stream>>>(attnP, temperature, attn);
        k_av_proj<<<512, 256, 0, stream>>>(qkvB, attn, w_proj, bufO);
        k_fuse<<<1024, 256, 0, stream>>>(bufO, w_fuse, bn_gamma, bn_beta,
                                         bn_mean, bn_var, yg, outg);
    }
}